// Round 5
// baseline (273.908 us; speedup 1.0000x reference)
//
#include <hip/hip_runtime.h>
#include <math.h>

#define T_TOTAL 262144
#define HIDN 20
#define IND 9
#define CHUNK 256
#define WARM 96
#define MAXST (WARM + CHUNK + 1)   // 353 rows
#define NBLK (T_TOTAL / CHUNK)     // 1024 blocks

typedef float float4v __attribute__((ext_vector_type(4)));

__device__ __forceinline__ float fexp(float x) {
    return __builtin_amdgcn_exp2f(x * 1.44269504088896340736f);
}
__device__ __forceinline__ float sigf(float x) {
    return __builtin_amdgcn_rcpf(1.0f + fexp(-x));
}
__device__ __forceinline__ float tanhfst(float x) {
    return 1.0f - 2.0f * __builtin_amdgcn_rcpf(1.0f + fexp(2.0f * x));
}
__device__ __forceinline__ float hsum4(float4v a) {
    return (a.x + a.y) + (a.z + a.w);
}

// 2-wave task split (128 threads), each lane holds only 2 gate-rows so the
// whole resident set (~115 VGPR) fits under the allocator's budget — round
// 2-4 showed a 64-lane/4-gate layout spills ~50 regs (VGPR stuck at 132).
//   tid 0..39   : layer-1, unit k=tid>>1, pair p=tid&1 (p0: gates i,f; p1: g,o),
//                 full 29-term rows (20 h1-terms + 9 x-terms).
//   tid 40..119 : layer-2 quads. u=(tid-40)>>2 = unit k; sub=(tid-40)&3:
//                 bit1=pair, bit0=part (0: W_ih2·h1, 1: W_hh2·h2), 20-term rows.
//   tid 120..127: idle (zero weights).
// Gate combine: 6 independent shfls within the (wave-aligned) quad.
__global__ __launch_bounds__(128, 2)
void lstm_scan(const float* __restrict__ x,
               const float* __restrict__ w_ih1, const float* __restrict__ w_hh1,
               const float* __restrict__ b1,
               const float* __restrict__ w_ih2, const float* __restrict__ w_hh2,
               const float* __restrict__ b2,
               const float* __restrict__ w_p, const float* __restrict__ b_p,
               float* __restrict__ out)
{
    __shared__ __align__(16) float xbuf[MAXST * 12];  // stride 12 floats (48B)
    __shared__ __align__(16) float hcur[64];          // h1@[0..19], h2@[32..51]
    __shared__ __align__(16) float h2out[CHUNK * HIDN];

    const int tid = threadIdx.x;
    const int blk = blockIdx.x;
    const int t0  = blk * CHUNK;
    const int start = (t0 >= WARM) ? (t0 - WARM) : 0;
    const int endt  = t0 + CHUNK;
    const int nst   = endt - start + 1;

    // ---- stage x chunk into LDS (coalesced; clamp last row)
    for (int idx = tid; idx < nst * IND; idx += 128) {
        int stp = idx / IND, d = idx - stp * IND;
        int gt = start + stp; if (gt > T_TOTAL - 1) gt = T_TOTAL - 1;
        xbuf[stp * 12 + d] = x[gt * IND + d];
    }
    if (tid < 64) hcur[tid] = 0.0f;

    // ---- role decode
    const bool isL1 = (tid < 40);
    const bool idle = (tid >= 120);
    int k, pair, part;
    const float* Wh;
    if (isL1) { k = tid >> 1; pair = tid & 1; part = 0; Wh = w_hh1; }
    else {
        int t2 = idle ? 0 : (tid - 40);
        k = t2 >> 2;
        int sub = t2 & 3;
        pair = sub >> 1; part = sub & 1;
        Wh = part ? w_hh2 : w_ih2;
    }
    const float scale = idle ? 0.0f : 1.0f;
    const int r0 = (2 * pair) * HIDN + k;
    const int r1 = (2 * pair + 1) * HIDN + k;

    // ---- 2 gate-rows of 20 h-terms (rows are 80B -> float4-aligned)
    float4v wa0, wa1, wa2, wa3, wa4, wb0, wb1, wb2, wb3, wb4;
    {
        const float4v* pa = (const float4v*)(Wh + r0 * HIDN);
        const float4v* pb = (const float4v*)(Wh + r1 * HIDN);
        wa0 = scale * pa[0]; wa1 = scale * pa[1]; wa2 = scale * pa[2];
        wa3 = scale * pa[3]; wa4 = scale * pa[4];
        wb0 = scale * pb[0]; wb1 = scale * pb[1]; wb2 = scale * pb[2];
        wb3 = scale * pb[3]; wb4 = scale * pb[4];
    }
    // ---- x-rows (layer-1 lanes only; rows of 9, scalar loads once)
    float4v xa0 = (float4v)0.f, xa1 = (float4v)0.f, xb0 = (float4v)0.f, xb1 = (float4v)0.f;
    float xa8 = 0.f, xb8 = 0.f, bA = 0.f, bB = 0.f;
    if (isL1) {
        const float* ra = w_ih1 + r0 * IND;
        const float* rb = w_ih1 + r1 * IND;
        xa0 = (float4v){ra[0], ra[1], ra[2], ra[3]};
        xa1 = (float4v){ra[4], ra[5], ra[6], ra[7]}; xa8 = ra[8];
        xb0 = (float4v){rb[0], rb[1], rb[2], rb[3]};
        xb1 = (float4v){rb[4], rb[5], rb[6], rb[7]}; xb8 = rb[8];
        bA = b1[r0]; bB = b1[r1];
    } else if (!idle && part == 0) {
        bA = b2[r0]; bB = b2[r1];
    }

    const float* vbase = (part == 1) ? (hcur + 32) : hcur;
    const bool ownL1 = isL1 && ((tid & 1) == 0);
    const bool ownL2 = (!isL1) && (!idle) && (((tid - 40) & 3) == 0);
    const float mL2  = isL1 ? 0.0f : 1.0f;
    const int  hslot = ownL1 ? k : (32 + k);

    __syncthreads();

    float c = 0.0f, h = 0.0f;

    // ---- peeled first step (s == start): h_prev = 0 -> x-terms + bias only
    {
        const float* xr = &xbuf[0];
        float4v xv0 = *(const float4v*)xr, xv1 = *(const float4v*)(xr + 4);
        float xv8 = xr[8];
        float4v sa = xa0 * xv0 + xa1 * xv1;
        float4v sb = xb0 * xv0 + xb1 * xv1;
        float d0 = hsum4(sa) + fmaf(xa8, xv8, bA);
        float d1 = hsum4(sb) + fmaf(xb8, xv8, bB);
        float s01 = __shfl(d0, tid + 1, 64);
        float s11 = __shfl(d1, tid + 1, 64);
        // L1 owner: a = (d0, d1, s01, s11); layer-2 output suppressed (warmup)
        float gi = sigf(d0), gf = sigf(d1), gg = tanhfst(s01), go = sigf(s11);
        float cn = gi * gg;                 // c was 0
        float hn = go * tanhfst(cn);
        if (ownL1) { c = cn; h = hn; hcur[k] = h; }
        (void)gf;
        __syncthreads();
    }

    // ---- main loop: s = start+1 .. endt
    for (int s = start + 1; s <= endt; ++s) {
        const float4v* vb4 = (const float4v*)vbase;
        float4v v0 = vb4[0], v1 = vb4[1], v2 = vb4[2], v3 = vb4[3], v4 = vb4[4];

        const float* xr = &xbuf[(s - start) * 12];
        float4v xv0 = *(const float4v*)xr, xv1 = *(const float4v*)(xr + 4);
        float xv8 = xr[8];

        float4v sa = wa0 * v0; sa += wa1 * v1; sa += wa2 * v2; sa += wa3 * v3; sa += wa4 * v4;
        float4v sb = wb0 * v0; sb += wb1 * v1; sb += wb2 * v2; sb += wb3 * v3; sb += wb4 * v4;
        sa += xa0 * xv0 + xa1 * xv1;        // zero vectors for non-L1 lanes
        sb += xb0 * xv0 + xb1 * xv1;
        float d0 = hsum4(sa) + fmaf(xa8, xv8, bA);
        float d1 = hsum4(sb) + fmaf(xb8, xv8, bB);

        // quad combine: 6 independent shfls (single LDS-pipe latency)
        float s01 = __shfl(d0, tid + 1, 64), s11 = __shfl(d1, tid + 1, 64);
        float s02 = __shfl(d0, tid + 2, 64), s12 = __shfl(d1, tid + 2, 64);
        float s03 = __shfl(d0, tid + 3, 64), s13 = __shfl(d1, tid + 3, 64);

        // L1 owner: a = (d0, d1, s01, s11)
        // L2 owner: a_i = d0+s01, a_f = d1+s11, a_g = s02+s03, a_o = s12+s13
        float a_i = fmaf(mL2, s01, d0);
        float a_f = fmaf(mL2, s11, d1);
        float a_g = isL1 ? s01 : s02 + s03;
        float a_o = isL1 ? s11 : s12 + s13;

        float gi = sigf(a_i), gf = sigf(a_f), gg = tanhfst(a_g), go = sigf(a_o);
        c = fmaf(gf, c, gi * gg);
        h = go * tanhfst(c);

        if (ownL1 | ownL2) hcur[hslot] = h;
        if (ownL2 && s > t0) h2out[(s - 1 - t0) * HIDN + k] = h;

        __syncthreads();
    }

    // ---- projection epilogue: out[t] = w_p . h2[t] + b_p
    {
        const float4v* wp4 = (const float4v*)w_p;
        float4v p0 = wp4[0], p1 = wp4[1], p2 = wp4[2], p3 = wp4[3], p4 = wp4[4];
        const float bp = b_p[0];
        for (int tt = tid; tt < CHUNK; tt += 128) {
            const float4v* hr = (const float4v*)(h2out + tt * HIDN);
            float4v s_ = p0 * hr[0];
            s_ += p1 * hr[1]; s_ += p2 * hr[2]; s_ += p3 * hr[3]; s_ += p4 * hr[4];
            out[t0 + tt] = hsum4(s_) + bp;
        }
    }
}

extern "C" void kernel_launch(void* const* d_in, const int* in_sizes, int n_in,
                              void* d_out, int out_size, void* d_ws, size_t ws_size,
                              hipStream_t stream) {
    const float* x     = (const float*)d_in[0];
    const float* w_ih1 = (const float*)d_in[1];
    const float* w_hh1 = (const float*)d_in[2];
    const float* b1    = (const float*)d_in[3];
    const float* w_ih2 = (const float*)d_in[4];
    const float* w_hh2 = (const float*)d_in[5];
    const float* b2    = (const float*)d_in[6];
    const float* w_p   = (const float*)d_in[7];
    const float* b_p   = (const float*)d_in[8];
    float* out = (float*)d_out;

    lstm_scan<<<NBLK, 128, 0, stream>>>(x, w_ih1, w_hh1, b1,
                                        w_ih2, w_hh2, b2, w_p, b_p, out);
}

// Round 6
// 186.812 us; speedup vs baseline: 1.4662x; 1.4662x over previous
//
#include <hip/hip_runtime.h>
#include <math.h>

#define T_TOTAL 262144
#define HIDN 20
#define IND 9
#define CHUNK 128
#define WARM 48
#define MAXST (WARM + CHUNK + 1)   // 177 rows
#define NBLK (T_TOTAL / CHUNK)     // 2048 blocks -> 8 blocks/CU resident

typedef float float4v __attribute__((ext_vector_type(4)));

__device__ __forceinline__ float fexp(float x) {
    return __builtin_amdgcn_exp2f(x * 1.44269504088896340736f);
}
__device__ __forceinline__ float sigf(float x) {
    return __builtin_amdgcn_rcpf(1.0f + fexp(-x));
}
__device__ __forceinline__ float tanhfst(float x) {
    return 1.0f - 2.0f * __builtin_amdgcn_rcpf(1.0f + fexp(2.0f * x));
}
__device__ __forceinline__ float hsum4(float4v a) {
    return (a.x + a.y) + (a.z + a.w);
}

#define DECLW(q) \
    float4v wv##q##0, wv##q##1, wv##q##2, wv##q##3, wv##q##4; \
    float4v wx##q##0, wx##q##1; float wx##q##8; float bq##q;

#define LOADW(q) { \
    const float4v* wr = (const float4v*)(wbase + ((q) * HIDN + krow) * HIDN); \
    wv##q##0 = scale * wr[0]; wv##q##1 = scale * wr[1]; wv##q##2 = scale * wr[2]; \
    wv##q##3 = scale * wr[3]; wv##q##4 = scale * wr[4]; \
    wx##q##0 = (float4v)0.0f; wx##q##1 = (float4v)0.0f; wx##q##8 = 0.0f; \
    if (grp == 0) { \
        const float* r = w_ih1 + ((q) * HIDN + k) * IND; \
        wx##q##0 = (float4v){r[0], r[1], r[2], r[3]}; \
        wx##q##1 = (float4v){r[4], r[5], r[6], r[7]}; \
        wx##q##8 = r[8]; \
    } \
    bq##q = (grp == 0) ? b1[(q) * HIDN + k] : ((grp == 1) ? b2[(q) * HIDN + k] : 0.0f); \
}

#define GATE(q) ({ \
    float4v s_ = wv##q##0 * v0; \
    s_ += wv##q##1 * v1; s_ += wv##q##2 * v2; \
    s_ += wv##q##3 * v3; s_ += wv##q##4 * v4; \
    s_ += wx##q##0 * xv0; s_ += wx##q##1 * xv1; \
    hsum4(s_) + fmaf(wx##q##8, xv8, bq##q); })

#define GATEX(q) ({ \
    float4v s_ = wx##q##0 * xv0 + wx##q##1 * xv1; \
    hsum4(s_) + fmaf(wx##q##8, xv8, bq##q); })

// Lanes 0-19: layer1 unit k. Lanes 20-39: layer2 W_ih2 half (state owner).
// Lanes 40-59: layer2 W_hh2 half. Lanes 60-63: zero weights (idle).
// Layer 2 runs one step behind layer 1 (reads h1[t-1] from hcur).
__global__ __launch_bounds__(64)
void lstm_scan(const float* __restrict__ x,
               const float* __restrict__ w_ih1, const float* __restrict__ w_hh1,
               const float* __restrict__ b1,
               const float* __restrict__ w_ih2, const float* __restrict__ w_hh2,
               const float* __restrict__ b2,
               const float* __restrict__ w_p, const float* __restrict__ b_p,
               float* __restrict__ out)
{
    __shared__ __align__(16) float xbuf[MAXST * 12];   // stride 12 floats (48B)
    __shared__ __align__(16) float hcur[64];           // h1@[0..19], h2@[32..51]
    __shared__ __align__(16) float h2out[CHUNK * HIDN];

    const int lane = threadIdx.x;
    const int blk  = blockIdx.x;
    const int t0   = blk * CHUNK;
    const int start = (t0 >= WARM) ? (t0 - WARM) : 0;
    const int endt  = t0 + CHUNK;
    const int nst   = endt - start + 1;

    // ---- stage x chunk into LDS (coalesced; clamp last padded row)
    for (int idx = lane; idx < nst * IND; idx += 64) {
        int stp = idx / IND, d = idx - stp * IND;
        int gt = start + stp; if (gt > T_TOTAL - 1) gt = T_TOTAL - 1;
        xbuf[stp * 12 + d] = x[gt * IND + d];
    }
    hcur[lane] = 0.0f;

    // ---- per-lane weights in named float4 registers
    const int grp  = lane / 20;
    const int k    = lane - grp * 20;
    const int krow = (grp < 3) ? k : 0;
    const float scale = (grp < 3) ? 1.0f : 0.0f;
    const float* wbase = (grp == 1) ? w_ih2 : ((grp == 2) ? w_hh2 : w_hh1);

    DECLW(0) DECLW(1) DECLW(2) DECLW(3)
    LOADW(0) LOADW(1) LOADW(2) LOADW(3)

    const float* vbase = (lane < 40) ? hcur : (hcur + 32);
    const bool  isl2   = (lane >= 20 && lane < 40);
    const float m2     = isl2 ? 1.0f : 0.0f;
    const int   h2col  = lane - 20;
    const int   hslot  = (lane < 20) ? lane : (32 + h2col);
    const int   shsrc  = (lane + 20) & 63;

    __syncthreads();

    float c = 0.0f, h = 0.0f;

    // ---- peeled first step (s == start): h,c zero -> x-only gates, L1 commits
    {
        const float* xr = &xbuf[0];
        float4v xv0 = *(const float4v*)xr, xv1 = *(const float4v*)(xr + 4);
        float xv8 = xr[8];
        float a0 = GATEX(0), a1 = GATEX(1), a2 = GATEX(2), a3 = GATEX(3);
        float gi = sigf(a0), gg = tanhfst(a2), go = sigf(a3);
        (void)a1;
        float cn = gi * gg;       // c was 0
        float hn = go * tanhfst(cn);
        c = (lane < 20) ? cn : 0.0f;
        h = (lane < 20) ? hn : 0.0f;
        if (lane < 40) hcur[hslot] = h;   // layer-2 slots stay 0
        __syncthreads();
    }

    // ---- main loop: s = start+1 .. endt
    for (int s = start + 1; s <= endt; ++s) {
        const float4v* vb4 = (const float4v*)vbase;
        float4v v0 = vb4[0], v1 = vb4[1], v2 = vb4[2], v3 = vb4[3], v4 = vb4[4];

        const float* xr = &xbuf[(s - start) * 12];
        float4v xv0 = *(const float4v*)xr, xv1 = *(const float4v*)(xr + 4);
        float xv8 = xr[8];

        float a0 = GATE(0), a1 = GATE(1), a2 = GATE(2), a3 = GATE(3);

        // layer-2 combine: lane 20+k += lane 40+k (masked fma)
        a0 = fmaf(m2, __shfl(a0, shsrc, 64), a0);
        a1 = fmaf(m2, __shfl(a1, shsrc, 64), a1);
        a2 = fmaf(m2, __shfl(a2, shsrc, 64), a2);
        a3 = fmaf(m2, __shfl(a3, shsrc, 64), a3);

        float gi = sigf(a0), gf = sigf(a1), gg = tanhfst(a2), go = sigf(a3);
        c = fmaf(gf, c, gi * gg);
        h = go * tanhfst(c);

        if (lane < 40) hcur[hslot] = h;                // 2-way bank alias: free
        if (isl2 && s > t0) h2out[(s - 1 - t0) * HIDN + h2col] = h;

        __syncthreads();
    }

    // ---- projection epilogue: out[t] = w_p . h2[t] + b_p
    {
        const float4v* wp4 = (const float4v*)w_p;
        float4v p0 = wp4[0], p1 = wp4[1], p2 = wp4[2], p3 = wp4[3], p4 = wp4[4];
        const float bp = b_p[0];
        for (int tt = lane; tt < CHUNK; tt += 64) {
            const float4v* hr = (const float4v*)(h2out + tt * HIDN);
            float4v s_ = p0 * hr[0];
            s_ += p1 * hr[1]; s_ += p2 * hr[2]; s_ += p3 * hr[3]; s_ += p4 * hr[4];
            out[t0 + tt] = hsum4(s_) + bp;
        }
    }
}

extern "C" void kernel_launch(void* const* d_in, const int* in_sizes, int n_in,
                              void* d_out, int out_size, void* d_ws, size_t ws_size,
                              hipStream_t stream) {
    const float* x     = (const float*)d_in[0];
    const float* w_ih1 = (const float*)d_in[1];
    const float* w_hh1 = (const float*)d_in[2];
    const float* b1    = (const float*)d_in[3];
    const float* w_ih2 = (const float*)d_in[4];
    const float* w_hh2 = (const float*)d_in[5];
    const float* b2    = (const float*)d_in[6];
    const float* w_p   = (const float*)d_in[7];
    const float* b_p   = (const float*)d_in[8];
    float* out = (float*)d_out;

    lstm_scan<<<NBLK, 64, 0, stream>>>(x, w_ih1, w_hh1, b1,
                                       w_ih2, w_hh2, b2, w_p, b_p, out);
}